// Round 5
// baseline (291.810 us; speedup 1.0000x reference)
//
#include <hip/hip_runtime.h>
#include <math.h>

#define BATCH 64
#define CC    256
#define ATTRN 300
#define DD    256
#define HW    784
#define O1    32
#define TILE3 128
#define NT3   7     // ceil(784/128)

// ws layout (floats):
// [0, 16384)             : sx    [64][256]
// [16384, 16384+524288)  : corrT [64][256 t][32 o]   (t-major, o contiguous)

// ---------------------------------------------------------------- k1
__global__ __launch_bounds__(256) void k1_emb_sketch(
    const float* __restrict__ attr_one_hot,
    const float* __restrict__ W_emb,
    const float* __restrict__ b_emb,
    const int*   __restrict__ h1,
    const float* __restrict__ s1,
    float* __restrict__ sx)
{
    const int b = blockIdx.x, t = threadIdx.x;
    __shared__ float s_attr[ATTRN];
    __shared__ float s_W[256 * 36];
    __shared__ float s_sx[DD];

    s_attr[t] = attr_one_hot[b * ATTRN + t];
    if (t < ATTRN - 256) s_attr[256 + t] = attr_one_hot[b * ATTRN + 256 + t];
    s_sx[t] = 0.f;

    float acc = b_emb[t];
    for (int a0 = 0; a0 < ATTRN; a0 += 32) {
        __syncthreads();
        const int ncol = (ATTRN - a0) < 32 ? (ATTRN - a0) : 32;
        const int nf4 = ncol >> 2;
        for (int i = t; i < 256 * nf4; i += 256) {
            int r = i / nf4, v = i - r * nf4;
            float4 w = *(const float4*)(W_emb + r * ATTRN + a0 + 4 * v);
            *(float4*)(&s_W[r * 36 + 4 * v]) = w;
        }
        __syncthreads();
        for (int v = 0; v < nf4; ++v) {
            float4 wv = *(const float4*)(&s_W[t * 36 + 4 * v]);
            acc += s_attr[a0 + 4 * v]     * wv.x;
            acc += s_attr[a0 + 4 * v + 1] * wv.y;
            acc += s_attr[a0 + 4 * v + 2] * wv.z;
            acc += s_attr[a0 + 4 * v + 3] * wv.w;
        }
    }
    __syncthreads();
    atomicAdd(&s_sx[h1[t]], acc * s1[t]);
    __syncthreads();
    sx[b * DD + t] = s_sx[t];
}

// ---------------------------------------------------------------- k2
// corrT[b][t][o] = sum_k conv1_w[o][k] * sx[b][(k-t)&255]
// conv1_w broadcast from LDS (not global); sx rotated reads conflict-free.
__global__ __launch_bounds__(256) void k2_corr(
    const float* __restrict__ sx,
    const float* __restrict__ conv1_w,
    float* __restrict__ corrT)
{
    const int b = blockIdx.x, og = blockIdx.y, t = threadIdx.x;
    const int o0 = og * 8;
    __shared__ float s_sx[DD];
    __shared__ float s_w1[8][DD];
    __shared__ float s_c[8][DD];

    s_sx[t] = sx[b * DD + t];
#pragma unroll
    for (int j = 0; j < 8; ++j) s_w1[j][t] = conv1_w[(o0 + j) * CC + t];
    __syncthreads();

    float acc[8] = {0.f,0.f,0.f,0.f,0.f,0.f,0.f,0.f};
    for (int k4 = 0; k4 < 64; ++k4) {
        const int k = k4 * 4;
        float x0 = s_sx[(k     - t) & 255];
        float x1 = s_sx[(k + 1 - t) & 255];
        float x2 = s_sx[(k + 2 - t) & 255];
        float x3 = s_sx[(k + 3 - t) & 255];
#pragma unroll
        for (int oo = 0; oo < 8; ++oo) {
            float4 w = *(const float4*)&s_w1[oo][k];   // LDS broadcast
            acc[oo] += w.x * x0 + w.y * x1 + w.z * x2 + w.w * x3;
        }
    }
#pragma unroll
    for (int oo = 0; oo < 8; ++oo) s_c[oo][t] = acc[oo];
    __syncthreads();

    float4 r0, r1;
    r0.x = s_c[0][t]; r0.y = s_c[1][t]; r0.z = s_c[2][t]; r0.w = s_c[3][t];
    r1.x = s_c[4][t]; r1.y = s_c[5][t]; r1.z = s_c[6][t]; r1.w = s_c[7][t];
    float4* dst = (float4*)(corrT + ((size_t)b * DD + t) * O1 + o0);
    dst[0] = r0; dst[1] = r1;
}

// ---------------------------------------------------------------- k3
// Fused: P-gather into LDS, hidden = P^T-style rank-1 accumulation
// (o-split waves, 2 locs/lane), conv2+sigmoid, scaled output pass.
__global__ __launch_bounds__(256) void k3_main(
    const float* __restrict__ ent,
    const float* __restrict__ corrT,
    const int*   __restrict__ h2,
    const float* __restrict__ s2,
    const float* __restrict__ conv2_w,
    float* __restrict__ out_map,
    float* __restrict__ out_feat)
{
    const int b = blockIdx.x, tile = blockIdx.y;
    const int tid = threadIdx.x;
    const int w = tid >> 6, lane = tid & 63;

    __shared__ float Pl[CC][36];        // P[c][o], pitch 36 (bank spread for writes)
    __shared__ float s_red[4][2][64];
    __shared__ float s_amap[TILE3];

    // ---- stage P: thread t handles c = t: P[c][o] = s2[c] * corrT[b][h2[c]][o]
    {
        const int c = tid;
        const int hc = h2[c];
        const float sc = s2[c];
        const float4* src = (const float4*)(corrT + ((size_t)b * DD + hc) * O1);
        float4 v[8];
#pragma unroll
        for (int j = 0; j < 8; ++j) v[j] = src[j];
#pragma unroll
        for (int j = 0; j < 8; ++j) {
            float4 x = v[j];
            x.x *= sc; x.y *= sc; x.z *= sc; x.w *= sc;
            *(float4*)&Pl[c][4 * j] = x;
        }
    }
    __syncthreads();

    const int o0 = w * 8;
    const int loc0 = tile * TILE3 + lane;
    const int loc1 = loc0 + 64;
    const bool v0 = loc0 < HW, v1 = loc1 < HW;
    const int l0 = v0 ? loc0 : (HW - 1);
    const int l1 = v1 ? loc1 : (HW - 1);
    const float* eb = ent + (size_t)b * CC * HW;

    float4 aA0 = make_float4(0.f,0.f,0.f,0.f), aB0 = aA0, aA1 = aA0, aB1 = aA0;

#pragma unroll 2
    for (int c = 0; c < CC; ++c) {
        float e0 = eb[c * HW + l0];
        float e1 = eb[c * HW + l1];
        asm volatile("" : "+v"(e0), "+v"(e1));   // pin loop structure
        float4 pA = *(const float4*)&Pl[c][o0];      // broadcast ds_read_b128
        float4 pB = *(const float4*)&Pl[c][o0 + 4];
        aA0.x += pA.x*e0; aA0.y += pA.y*e0; aA0.z += pA.z*e0; aA0.w += pA.w*e0;
        aB0.x += pB.x*e0; aB0.y += pB.y*e0; aB0.z += pB.z*e0; aB0.w += pB.w*e0;
        aA1.x += pA.x*e1; aA1.y += pA.y*e1; aA1.z += pA.z*e1; aA1.w += pA.w*e1;
        aB1.x += pB.x*e1; aB1.y += pB.y*e1; aB1.z += pB.z*e1; aB1.w += pB.w*e1;
    }

    // ---- conv2 partials (per wave: its 8 o's), then cross-wave reduce
    {
        float p0 = 0.f, p1 = 0.f;
        p0 += conv2_w[o0+0] * fmaxf(aA0.x, 0.f);
        p0 += conv2_w[o0+1] * fmaxf(aA0.y, 0.f);
        p0 += conv2_w[o0+2] * fmaxf(aA0.z, 0.f);
        p0 += conv2_w[o0+3] * fmaxf(aA0.w, 0.f);
        p0 += conv2_w[o0+4] * fmaxf(aB0.x, 0.f);
        p0 += conv2_w[o0+5] * fmaxf(aB0.y, 0.f);
        p0 += conv2_w[o0+6] * fmaxf(aB0.z, 0.f);
        p0 += conv2_w[o0+7] * fmaxf(aB0.w, 0.f);
        p1 += conv2_w[o0+0] * fmaxf(aA1.x, 0.f);
        p1 += conv2_w[o0+1] * fmaxf(aA1.y, 0.f);
        p1 += conv2_w[o0+2] * fmaxf(aA1.z, 0.f);
        p1 += conv2_w[o0+3] * fmaxf(aA1.w, 0.f);
        p1 += conv2_w[o0+4] * fmaxf(aB1.x, 0.f);
        p1 += conv2_w[o0+5] * fmaxf(aB1.y, 0.f);
        p1 += conv2_w[o0+6] * fmaxf(aB1.z, 0.f);
        p1 += conv2_w[o0+7] * fmaxf(aB1.w, 0.f);
        s_red[w][0][lane] = p0;
        s_red[w][1][lane] = p1;
    }
    __syncthreads();

    if (tid < TILE3) {
        const int set = tid >> 6, l = tid & 63;
        float pre = s_red[0][set][l] + s_red[1][set][l]
                  + s_red[2][set][l] + s_red[3][set][l];
        float am = 1.f / (1.f + expf(-pre));
        s_amap[tid] = am;
        int loc = tile * TILE3 + tid;
        if (loc < HW) out_map[b * HW + loc] = am;
    }
    __syncthreads();

    // ---- output pass: each wave takes a 64-c range, descending (cache-hot)
    {
        const float am0 = s_amap[lane];
        const float am1 = s_amap[64 + lane];
        for (int i = 0; i < 64; ++i) {
            int c = 255 - (w * 64 + i);
            float e0 = eb[c * HW + l0];
            float e1 = eb[c * HW + l1];
            if (v0) out_feat[((size_t)b * CC + c) * HW + loc0] = am0 * e0;
            if (v1) out_feat[((size_t)b * CC + c) * HW + loc1] = am1 * e1;
        }
    }
}

extern "C" void kernel_launch(void* const* d_in, const int* in_sizes, int n_in,
                              void* d_out, int out_size, void* d_ws, size_t ws_size,
                              hipStream_t stream) {
    const float* ent   = (const float*)d_in[0];
    const float* attr  = (const float*)d_in[1];
    const float* W_emb = (const float*)d_in[2];
    const float* b_emb = (const float*)d_in[3];
    const int*   h1    = (const int*)d_in[4];
    const float* s1    = (const float*)d_in[5];
    const int*   h2    = (const int*)d_in[6];
    const float* s2    = (const float*)d_in[7];
    const float* c1w   = (const float*)d_in[8];
    const float* c2w   = (const float*)d_in[9];

    float* ws    = (float*)d_ws;
    float* sx    = ws;
    float* corrT = ws + 16384;

    float* out      = (float*)d_out;
    float* out_map  = out;                 // [64,1,28,28]
    float* out_feat = out + BATCH * HW;    // [64,256,28,28]

    hipLaunchKernelGGL(k1_emb_sketch, dim3(BATCH), dim3(256), 0, stream,
                       attr, W_emb, b_emb, h1, s1, sx);
    hipLaunchKernelGGL(k2_corr, dim3(BATCH, 4), dim3(256), 0, stream,
                       sx, c1w, corrT);
    hipLaunchKernelGGL(k3_main, dim3(BATCH, NT3), dim3(256), 0, stream,
                       ent, corrT, h2, s2, c2w, out_map, out_feat);
}

// Round 6
// 201.651 us; speedup vs baseline: 1.4471x; 1.4471x over previous
//
#include <hip/hip_runtime.h>
#include <math.h>

#define BATCH 64
#define CC    256
#define ATTRN 300
#define DD    256
#define HW    784
#define HW4   196   // HW / 4
#define O1    32
#define TF4   49    // float4 columns per tile (4 tiles * 49 * 4 = 784)

// ws layout (floats):
// [0, 16384)             : sx    [64][256]
// [16384, 16384+524288)  : corrT [64][256 t][32 o]   (t-major, o contiguous)

// ---------------------------------------------------------------- k1
__global__ __launch_bounds__(256) void k1_emb_sketch(
    const float* __restrict__ attr_one_hot,
    const float* __restrict__ W_emb,
    const float* __restrict__ b_emb,
    const int*   __restrict__ h1,
    const float* __restrict__ s1,
    float* __restrict__ sx)
{
    const int b = blockIdx.x, t = threadIdx.x;
    __shared__ float s_attr[ATTRN];
    __shared__ float s_W[256 * 36];
    __shared__ float s_sx[DD];

    s_attr[t] = attr_one_hot[b * ATTRN + t];
    if (t < ATTRN - 256) s_attr[256 + t] = attr_one_hot[b * ATTRN + 256 + t];
    s_sx[t] = 0.f;

    float acc = b_emb[t];
    for (int a0 = 0; a0 < ATTRN; a0 += 32) {
        __syncthreads();
        const int ncol = (ATTRN - a0) < 32 ? (ATTRN - a0) : 32;
        const int nf4 = ncol >> 2;
        for (int i = t; i < 256 * nf4; i += 256) {
            int r = i / nf4, v = i - r * nf4;
            float4 w = *(const float4*)(W_emb + r * ATTRN + a0 + 4 * v);
            *(float4*)(&s_W[r * 36 + 4 * v]) = w;
        }
        __syncthreads();
        for (int v = 0; v < nf4; ++v) {
            float4 wv = *(const float4*)(&s_W[t * 36 + 4 * v]);
            float4 av = *(const float4*)(&s_attr[a0 + 4 * v]);
            acc += av.x * wv.x + av.y * wv.y + av.z * wv.z + av.w * wv.w;
        }
    }
    __syncthreads();
    atomicAdd(&s_sx[h1[t]], acc * s1[t]);
    __syncthreads();
    sx[b * DD + t] = s_sx[t];
}

// ---------------------------------------------------------------- k2
// corrT[b][t][o] = sum_k conv1_w[o][k] * sx[b][(k-t)&255]
__global__ __launch_bounds__(256) void k2_corr(
    const float* __restrict__ sx,
    const float* __restrict__ conv1_w,
    float* __restrict__ corrT)
{
    const int b = blockIdx.x, og = blockIdx.y, t = threadIdx.x;
    const int o0 = og * 8;
    __shared__ float s_sx[DD];
    __shared__ float s_w1[8][DD];
    __shared__ float s_c[8][DD];

    s_sx[t] = sx[b * DD + t];
#pragma unroll
    for (int j = 0; j < 8; ++j) s_w1[j][t] = conv1_w[(o0 + j) * CC + t];
    __syncthreads();

    float acc[8] = {0.f,0.f,0.f,0.f,0.f,0.f,0.f,0.f};
    for (int k4 = 0; k4 < 64; ++k4) {
        const int k = k4 * 4;
        float x0 = s_sx[(k     - t) & 255];
        float x1 = s_sx[(k + 1 - t) & 255];
        float x2 = s_sx[(k + 2 - t) & 255];
        float x3 = s_sx[(k + 3 - t) & 255];
#pragma unroll
        for (int oo = 0; oo < 8; ++oo) {
            float4 w = *(const float4*)&s_w1[oo][k];
            acc[oo] += w.x * x0 + w.y * x1 + w.z * x2 + w.w * x3;
        }
    }
#pragma unroll
    for (int oo = 0; oo < 8; ++oo) s_c[oo][t] = acc[oo];
    __syncthreads();

    float4 r0, r1;
    r0.x = s_c[0][t]; r0.y = s_c[1][t]; r0.z = s_c[2][t]; r0.w = s_c[3][t];
    r1.x = s_c[4][t]; r1.y = s_c[5][t]; r1.z = s_c[6][t]; r1.w = s_c[7][t];
    float4* dst = (float4*)(corrT + ((size_t)b * DD + t) * O1 + o0);
    dst[0] = r0; dst[1] = r1;
}

// ---------------------------------------------------------------- k3
// Grid (64 b, 4 tiles of 49 float4 = 196 locs). 4 waves split c (64 each).
// Per c-iter: 1 coalesced float4 ent load + 8 broadcast ds_read_b128 of P
// + 128 FMA into 32 float4 accs (o x 4locs). Cross-wave relu/conv2 reduce
// in 4 o-octet LDS passes. Float4 output pass.
#define FMA4(A, S, E) { (A).x += (S)*(E).x; (A).y += (S)*(E).y; (A).z += (S)*(E).z; (A).w += (S)*(E).w; }

__global__ __launch_bounds__(256, 1) void k3_main(
    const float* __restrict__ ent,
    const float* __restrict__ corrT,
    const int*   __restrict__ h2,
    const float* __restrict__ s2,
    const float* __restrict__ conv2_w,
    float* __restrict__ out_map,
    float* __restrict__ out_feat)
{
    const int b = blockIdx.x, tile = blockIdx.y;
    const int tid = threadIdx.x;
    const int w = tid >> 6, lane = tid & 63;

    __shared__ float  Pl[CC][32];          // broadcast-read only: pitch 32 fine
    __shared__ float4 s_p4[4][TF4][9];     // +1 f4 pad: 2-way max on reduce reads
    __shared__ float4 s_amap4[TF4];
    __shared__ float  s_c2[O1];

    // ---- stage P[c][o] = s2[c] * corrT[b][h2[c]][o]
    {
        const int c = tid;
        const int hc = h2[c];
        const float sc = s2[c];
        const float4* src = (const float4*)(corrT + ((size_t)b * DD + hc) * O1);
#pragma unroll
        for (int q = 0; q < 8; ++q) {
            float4 x = src[q];
            x.x *= sc; x.y *= sc; x.z *= sc; x.w *= sc;
            *(float4*)&Pl[c][4 * q] = x;
        }
        if (tid < O1) s_c2[tid] = conv2_w[tid];
    }
    __syncthreads();

    const bool act = lane < TF4;
    const int f4i = tile * TF4 + (act ? lane : TF4 - 1);
    const float4* ent4 = (const float4*)ent;
    const int c0 = w * 64;

    float4 acc[32];
#pragma unroll
    for (int o = 0; o < 32; ++o) acc[o] = make_float4(0.f, 0.f, 0.f, 0.f);

#pragma unroll 2
    for (int cc = 0; cc < 64; ++cc) {
        const int c = c0 + cc;
        float4 e4 = ent4[(size_t)(b * CC + c) * HW4 + f4i];
        asm volatile("" : "+v"(e4.x), "+v"(e4.y), "+v"(e4.z), "+v"(e4.w));
#pragma unroll
        for (int q = 0; q < 8; ++q) {
            float4 p = *(const float4*)&Pl[c][4 * q];
            FMA4(acc[4*q+0], p.x, e4);
            FMA4(acc[4*q+1], p.y, e4);
            FMA4(acc[4*q+2], p.z, e4);
            FMA4(acc[4*q+3], p.w, e4);
        }
    }

    // ---- cross-wave reduce + relu + conv2, 4 o-octet passes
    float pre = 0.f;
#pragma unroll
    for (int g = 0; g < 4; ++g) {
        __syncthreads();
        if (act) {
#pragma unroll
            for (int i = 0; i < 8; ++i) s_p4[w][lane][i] = acc[8 * g + i];
        }
        __syncthreads();
        if (tid < 4 * TF4) {
            const int fi = tid >> 2, j = tid & 3;
#pragma unroll
            for (int i = 0; i < 8; ++i) {
                float v = ((const float*)&s_p4[0][fi][i])[j]
                        + ((const float*)&s_p4[1][fi][i])[j]
                        + ((const float*)&s_p4[2][fi][i])[j]
                        + ((const float*)&s_p4[3][fi][i])[j];
                pre += s_c2[8 * g + i] * fmaxf(v, 0.f);
            }
        }
    }
    __syncthreads();
    if (tid < 4 * TF4) {
        const int fi = tid >> 2, j = tid & 3;
        float am = 1.f / (1.f + expf(-pre));
        ((float*)&s_amap4[fi])[j] = am;
        out_map[b * HW + tile * (4 * TF4) + tid] = am;
    }
    __syncthreads();

    // ---- output pass: wave re-walks its own c-range (L2-hot), float4 I/O
    const float4 am4 = s_amap4[act ? lane : 0];
    float4* of4 = (float4*)out_feat;
#pragma unroll 4
    for (int cc = 0; cc < 64; ++cc) {
        const int c = c0 + cc;
        if (act) {
            const size_t idx = (size_t)(b * CC + c) * HW4 + f4i;
            float4 e4 = ent4[idx];
            float4 r;
            r.x = am4.x * e4.x; r.y = am4.y * e4.y;
            r.z = am4.z * e4.z; r.w = am4.w * e4.w;
            of4[idx] = r;
        }
    }
}

extern "C" void kernel_launch(void* const* d_in, const int* in_sizes, int n_in,
                              void* d_out, int out_size, void* d_ws, size_t ws_size,
                              hipStream_t stream) {
    const float* ent   = (const float*)d_in[0];
    const float* attr  = (const float*)d_in[1];
    const float* W_emb = (const float*)d_in[2];
    const float* b_emb = (const float*)d_in[3];
    const int*   h1    = (const int*)d_in[4];
    const float* s1    = (const float*)d_in[5];
    const int*   h2    = (const int*)d_in[6];
    const float* s2    = (const float*)d_in[7];
    const float* c1w   = (const float*)d_in[8];
    const float* c2w   = (const float*)d_in[9];

    float* ws    = (float*)d_ws;
    float* sx    = ws;
    float* corrT = ws + 16384;

    float* out      = (float*)d_out;
    float* out_map  = out;                 // [64,1,28,28]
    float* out_feat = out + BATCH * HW;    // [64,256,28,28]

    hipLaunchKernelGGL(k1_emb_sketch, dim3(BATCH), dim3(256), 0, stream,
                       attr, W_emb, b_emb, h1, s1, sx);
    hipLaunchKernelGGL(k2_corr, dim3(BATCH, 4), dim3(256), 0, stream,
                       sx, c1w, corrT);
    hipLaunchKernelGGL(k3_main, dim3(BATCH, 4), dim3(256), 0, stream,
                       ent, corrT, h2, s2, c2w, out_map, out_feat);
}